// Round 4
// baseline (25.696 us; speedup 1.0000x reference)
//
#include <hip/hip_runtime.h>
#include <math.h>

// SmoothedMedian: B=32, L=1024, C=32, w=32
// out[0..31] = M (per-batch max over t of windowed max distance)
// out[32..63] = R2 (per-batch sum over t of (windowed max distance)^2)
//
// Single fused kernel. Per (batch, 64-center tile): banded Gram
// G[t,r] = dot(x_t,x_r) over 128 staged rows via split-bf16 MFMA:
//   x = hi + lo (bit-truncated);  G ~= Ah*Bh + Ah*Bl + Al*Bh  (err ~2^-16 rel)
//   sq(t,r) = n_t + n_r - 2*G[t,r]  (norms exact fp32)
// Cross-block reduce: last-block-done (device-scope fence + atomic counter),
// fixed-order tree => deterministic.
// mfma_f32_16x16x32_bf16: A lane l -> row l&15, k=(l>>4)*8+j (K-contig);
// B lane l -> col l&15, same k; D: col=l&15, row=(l>>4)*4+reg  [m89/m91].

#define BB 32
#define LL 1024
#define CC 32
#define WW 32
#define TT 64
#define NROWS (TT + 2*WW)     // 128
#define PADH 40               // bf16 elems/row (80 B): 16B-aligned, full bank coverage
#define NTILES (LL / TT)      // 16
#define NBLK (BB * NTILES)    // 512

typedef __attribute__((ext_vector_type(8))) short bf16x8;
typedef __attribute__((ext_vector_type(4))) float f32x4;

__global__ __launch_bounds__(256)
void sm_fused(const float* __restrict__ x, float* __restrict__ ws,
              int* __restrict__ cnt, float* __restrict__ out) {
    const int b    = blockIdx.x;
    const int tile = blockIdx.y;
    const int t0   = tile * TT;
    const int tid  = threadIdx.x;   // 0..255
    const int l    = tid & 63;      // lane
    const int w    = tid >> 6;      // wave 0..3

    __shared__ __align__(16) unsigned short hi[NROWS * PADH];
    __shared__ __align__(16) unsigned short lo[NROWS * PADH];
    __shared__ __align__(16) float nrm_part[NROWS * 8];
    __shared__ float nrm[NROWS];
    __shared__ float redm[16], redr[16];
    __shared__ int lastFlag;

    const float* xb = x + (size_t)b * (LL * CC);

    // --- stage 128 rows x 32 ch: fp32 load, split to bf16 hi/lo, norm partials ---
    #pragma unroll
    for (int k = 0; k < 4; ++k) {
        const int f4 = tid + k * 256;      // 0..1023
        const int rr = f4 >> 3;            // local row (8 float4/row)
        const int j  = f4 & 7;
        const int rg = t0 - WW + rr;       // global row
        float4 v = make_float4(0.f, 0.f, 0.f, 0.f);
        if ((unsigned)rg < (unsigned)LL)
            v = *reinterpret_cast<const float4*>(xb + rg * CC + j * 4);
        float vv[4] = {v.x, v.y, v.z, v.w};
        unsigned short hb[4], lb[4];
        float s = 0.f;
        #pragma unroll
        for (int e = 0; e < 4; ++e) {
            const float xe = vv[e];
            const unsigned ux = __float_as_uint(xe);
            hb[e] = (unsigned short)(ux >> 16);                  // truncate to bf16
            const float hf = __uint_as_float(ux & 0xFFFF0000u);
            const float lf = xe - hf;                            // exact residual
            lb[e] = (unsigned short)(__float_as_uint(lf) >> 16);
            s = fmaf(xe, xe, s);
        }
        *reinterpret_cast<ushort4*>(&hi[rr * PADH + j * 4]) = make_ushort4(hb[0], hb[1], hb[2], hb[3]);
        *reinterpret_cast<ushort4*>(&lo[rr * PADH + j * 4]) = make_ushort4(lb[0], lb[1], lb[2], lb[3]);
        nrm_part[f4] = s;
    }
    __syncthreads();

    if (tid < NROWS) {
        const float4* p = reinterpret_cast<const float4*>(&nrm_part[tid * 8]);
        const float4 a = p[0], c = p[1];
        nrm[tid] = ((a.x + a.y) + (a.z + a.w)) + ((c.x + c.y) + (c.z + c.w));
    }
    __syncthreads();

    // --- A-frag: wave w's 16 centers (local rows 32+16w .. 47+16w) ---
    const int kc = (l >> 4) * 8;
    const int ar = 32 + 16 * w + (l & 15);
    const bf16x8 Ah = *reinterpret_cast<const bf16x8*>(&hi[ar * PADH + kc]);
    const bf16x8 Al = *reinterpret_cast<const bf16x8*>(&lo[ar * PADH + kc]);

    const int col = l & 15;
    float maxsq[4] = {0.f, 0.f, 0.f, 0.f};   // o==0 contributes ~0; floor 0 correct

    // window rows for wave w's centers span local [16w, 16w+79] -> 5 B-tiles
    #pragma unroll
    for (int ct = 0; ct < 5; ++ct) {
        const int br = 16 * w + 16 * ct + col;   // local window row (this lane's col)
        const bf16x8 Bh = *reinterpret_cast<const bf16x8*>(&hi[br * PADH + kc]);
        const bf16x8 Bl = *reinterpret_cast<const bf16x8*>(&lo[br * PADH + kc]);
        f32x4 acc = {0.f, 0.f, 0.f, 0.f};
        acc = __builtin_amdgcn_mfma_f32_16x16x32_bf16(Ah, Bh, acc, 0, 0, 0);
        acc = __builtin_amdgcn_mfma_f32_16x16x32_bf16(Ah, Bl, acc, 0, 0, 0);
        acc = __builtin_amdgcn_mfma_f32_16x16x32_bf16(Al, Bh, acc, 0, 0, 0);

        const int rg = t0 - WW + br;             // global window row
        const float nr = nrm[br];
        #pragma unroll
        for (int i = 0; i < 4; ++i) {
            const int ic = 16 * w + (l >> 4) * 4 + i;   // center index 0..63
            // valid window: br in [ic, ic+64]; global row in [0,L)
            if (br >= ic && br <= ic + 64 && (unsigned)rg < (unsigned)LL) {
                const float sq = nrm[ic + 32] + nr - 2.0f * acc[i];
                maxsq[i] = fmaxf(maxsq[i], sq);
            }
        }
    }

    // --- 16-lane (col) reduce, then per-wave partials ---
    #pragma unroll
    for (int i = 0; i < 4; ++i) {
        float m = maxsq[i];
        #pragma unroll
        for (int s = 1; s < 16; s <<= 1) m = fmaxf(m, __shfl_xor(m, s));
        maxsq[i] = m;
    }
    if ((l & 15) == 0) {
        float dm = 0.f, r2 = 0.f;
        #pragma unroll
        for (int i = 0; i < 4; ++i) {
            const float d = sqrtf(fmaxf(maxsq[i], 0.f)) * (1.0f / CC);
            dm = fmaxf(dm, d);
            r2 = fmaf(d, d, r2);
        }
        redm[w * 4 + (l >> 4)] = dm;
        redr[w * 4 + (l >> 4)] = r2;
    }
    __syncthreads();

    // --- block partial -> slot; last-block-done handshake ---
    if (tid == 0) {
        float dm = redm[0], r2 = redr[0];
        #pragma unroll
        for (int g = 1; g < 16; ++g) { dm = fmaxf(dm, redm[g]); r2 += redr[g]; }
        float* slot = ws + (size_t)(b * NTILES + tile) * 2;
        slot[0] = dm;
        slot[1] = r2;
        __threadfence();                          // release (device scope)
        const int old = atomicAdd(cnt, 1);
        lastFlag = (old == NBLK - 1) ? 1 : 0;
    }
    __syncthreads();

    // --- final reduce by the last block (fixed order => deterministic) ---
    if (lastFlag) {
        __threadfence();                          // acquire
        const int bb = tid >> 3;                  // batch 0..31
        const int j  = tid & 7;                   // tile pair selector
        const float* s0 = ws + (size_t)(bb * NTILES + j) * 2;
        const float* s1 = ws + (size_t)(bb * NTILES + j + 8) * 2;
        float m  = fmaxf(s0[0], s1[0]);
        float r2 = s0[1] + s1[1];
        #pragma unroll
        for (int s = 1; s < 8; s <<= 1) {
            m  = fmaxf(m, __shfl_xor(m, s));
            r2 += __shfl_xor(r2, s);
        }
        if (j == 0) {
            out[bb]      = m;
            out[BB + bb] = r2;
        }
    }
}

extern "C" void kernel_launch(void* const* d_in, const int* in_sizes, int n_in,
                              void* d_out, int out_size, void* d_ws, size_t ws_size,
                              hipStream_t stream) {
    const float* x  = (const float*)d_in[0];   // (32,1024,32) fp32
    // d_in[1] is w == 32, hardcoded
    float* ws  = (float*)d_ws;                 // NBLK*2 floats = 4 KB slots
    int*   cnt = (int*)((char*)d_ws + NBLK * 2 * sizeof(float));
    float* out = (float*)d_out;                // 64 floats: M(32) ++ R2(32)

    hipMemsetAsync(cnt, 0, sizeof(int), stream);
    sm_fused<<<dim3(BB, NTILES), 256, 0, stream>>>(x, ws, cnt, out);
}

// Round 5
// 17.459 us; speedup vs baseline: 1.4718x; 1.4718x over previous
//
#include <hip/hip_runtime.h>
#include <math.h>

// SmoothedMedian: B=32, L=1024, C=32, w=32
// out[0..31] = M (per-batch max over t of windowed max distance)
// out[32..63] = R2 (per-batch sum over t of (windowed max distance)^2)
//
// ONE kernel, ONE block per batch (32 blocks x 1024 threads = 16 waves).
// No atomics / fences / memsets / second dispatch: each block reduces its
// batch fully in LDS (fixed order => deterministic) and plain-stores its
// two outputs.
//
// Math (verified rounds 3-4, absmax 0.0): banded Gram via split-bf16 MFMA,
//   x = hi + lo (bit-truncate);  G ~= Ah*Bh + Ah*Bl + Al*Bh  (err ~2^-16 rel)
//   sq(t,r) = n_t + n_r - 2*G[t,r]   (norms exact fp32)
//   maxsq[t] = max over valid r;  M = sqrt(max_t maxsq)/32; R2 = sum maxsq/1024
// mfma_f32_16x16x32_bf16: A lane l -> row l&15, k=(l>>4)*8+j (K-contig);
// B lane l -> col l&15, same k; D: col=l&15, row=(l>>4)*4+reg  [m89/m91].

#define BB 32
#define LL 1024
#define CC 32
#define WW 32
#define HF 512                // centers per mega-half
#define NR (HF + 2*WW)        // 576 staged rows per half
#define PADH 40               // bf16/row (80 B): 16B-aligned, full bank coverage

typedef __attribute__((ext_vector_type(8))) short bf16x8;
typedef __attribute__((ext_vector_type(4))) float f32x4;

__global__ __launch_bounds__(1024)
void sm_onepass(const float* __restrict__ x, float* __restrict__ out) {
    const int b   = blockIdx.x;
    const int tid = threadIdx.x;    // 0..1023
    const int l   = tid & 63;       // lane
    const int w   = tid >> 6;       // wave 0..15

    __shared__ __align__(16) unsigned short hi[NR * PADH];   // 46080 B
    __shared__ __align__(16) unsigned short lo[NR * PADH];   // 46080 B
    __shared__ __align__(16) float nrm_part[NR * 8];         // 18432 B
    __shared__ float nrm[NR];                                //  2304 B
    __shared__ float redm[64], redr[64];

    const float* xb = x + (size_t)b * (LL * CC);
    const int kc  = (l >> 4) * 8;   // this lane's channel offset in the frag
    const int col = l & 15;

    float dmsq = 0.0f;   // max over this thread's centers of maxsq
    float r2s  = 0.0f;   // sum over this thread's centers of maxsq

    for (int h = 0; h < 2; ++h) {
        const int g0 = h * HF - WW;   // global row of local row 0

        // --- stage NR rows x 32 ch: fp32 load, split bf16 hi/lo, norm partials ---
        // NR*8 = 4608 float4; threads do 4 full rounds + tail of 512.
        #pragma unroll
        for (int k = 0; k < 4; ++k) {
            const int f4 = tid + k * 1024;
            const int rr = f4 >> 3, j = f4 & 7;
            const int rg = g0 + rr;
            float4 v = make_float4(0.f, 0.f, 0.f, 0.f);
            if ((unsigned)rg < (unsigned)LL)
                v = *reinterpret_cast<const float4*>(xb + rg * CC + j * 4);
            float vv[4] = {v.x, v.y, v.z, v.w};
            unsigned short hb[4], lb[4];
            float s = 0.f;
            #pragma unroll
            for (int e = 0; e < 4; ++e) {
                const float xe = vv[e];
                const unsigned ux = __float_as_uint(xe);
                hb[e] = (unsigned short)(ux >> 16);
                const float hf = __uint_as_float(ux & 0xFFFF0000u);
                const float lf = xe - hf;                            // exact
                lb[e] = (unsigned short)(__float_as_uint(lf) >> 16);
                s = fmaf(xe, xe, s);
            }
            *reinterpret_cast<ushort4*>(&hi[rr * PADH + j * 4]) = make_ushort4(hb[0], hb[1], hb[2], hb[3]);
            *reinterpret_cast<ushort4*>(&lo[rr * PADH + j * 4]) = make_ushort4(lb[0], lb[1], lb[2], lb[3]);
            nrm_part[f4] = s;
        }
        if (tid < 512) {
            const int f4 = tid + 4096;
            const int rr = f4 >> 3, j = f4 & 7;
            const int rg = g0 + rr;
            float4 v = make_float4(0.f, 0.f, 0.f, 0.f);
            if ((unsigned)rg < (unsigned)LL)
                v = *reinterpret_cast<const float4*>(xb + rg * CC + j * 4);
            float vv[4] = {v.x, v.y, v.z, v.w};
            unsigned short hb[4], lb[4];
            float s = 0.f;
            #pragma unroll
            for (int e = 0; e < 4; ++e) {
                const float xe = vv[e];
                const unsigned ux = __float_as_uint(xe);
                hb[e] = (unsigned short)(ux >> 16);
                const float hf = __uint_as_float(ux & 0xFFFF0000u);
                const float lf = xe - hf;
                lb[e] = (unsigned short)(__float_as_uint(lf) >> 16);
                s = fmaf(xe, xe, s);
            }
            *reinterpret_cast<ushort4*>(&hi[rr * PADH + j * 4]) = make_ushort4(hb[0], hb[1], hb[2], hb[3]);
            *reinterpret_cast<ushort4*>(&lo[rr * PADH + j * 4]) = make_ushort4(lb[0], lb[1], lb[2], lb[3]);
            nrm_part[f4] = s;
        }
        __syncthreads();

        if (tid < NR) {
            const float4* p = reinterpret_cast<const float4*>(&nrm_part[tid * 8]);
            const float4 a = p[0], c = p[1];
            nrm[tid] = ((a.x + a.y) + (a.z + a.w)) + ((c.x + c.y) + (c.z + c.w));
        }
        __syncthreads();

        // --- MFMA: wave w owns centers [32w, 32w+32) of this half (2 A-frags) ---
        #pragma unroll
        for (int a = 0; a < 2; ++a) {
            const int arB = WW + 32 * w + 16 * a;   // A-frag base LDS row (32..528)
            const int ar  = arB + col;
            const bf16x8 Ah = *reinterpret_cast<const bf16x8*>(&hi[ar * PADH + kc]);
            const bf16x8 Al = *reinterpret_cast<const bf16x8*>(&lo[ar * PADH + kc]);

            float maxsq[4] = {0.f, 0.f, 0.f, 0.f};  // o==0 => 0 is correct floor

            #pragma unroll
            for (int ct = 0; ct < 5; ++ct) {
                const int br = arB - 32 + 16 * ct + col;   // window LDS row (this lane's col)
                const bf16x8 Bh = *reinterpret_cast<const bf16x8*>(&hi[br * PADH + kc]);
                const bf16x8 Bl = *reinterpret_cast<const bf16x8*>(&lo[br * PADH + kc]);
                f32x4 acc = {0.f, 0.f, 0.f, 0.f};
                acc = __builtin_amdgcn_mfma_f32_16x16x32_bf16(Ah, Bh, acc, 0, 0, 0);
                acc = __builtin_amdgcn_mfma_f32_16x16x32_bf16(Ah, Bl, acc, 0, 0, 0);
                acc = __builtin_amdgcn_mfma_f32_16x16x32_bf16(Al, Bh, acc, 0, 0, 0);

                const int rg = g0 + br;                    // global window row
                const float nr = nrm[br];
                #pragma unroll
                for (int i = 0; i < 4; ++i) {
                    const int crow = arB + (l >> 4) * 4 + i;   // center LDS row
                    if (br >= crow - 32 && br <= crow + 32 && (unsigned)rg < (unsigned)LL) {
                        const float sq = nrm[crow] + nr - 2.0f * acc[i];
                        maxsq[i] = fmaxf(maxsq[i], sq);
                    }
                }
            }

            // reduce over the 16 lanes sharing each center group, accumulate
            #pragma unroll
            for (int i = 0; i < 4; ++i) {
                float m = maxsq[i];
                #pragma unroll
                for (int s = 1; s < 16; s <<= 1) m = fmaxf(m, __shfl_xor(m, s));
                dmsq = fmaxf(dmsq, m);
                r2s += m;          // all 16 lanes of a subgroup identical; only col==0 used later
            }
        }
        __syncthreads();   // protect LDS before next half overwrites
    }

    // --- block reduce: 16 waves x 4 subgroups, fixed order => deterministic ---
    if ((l & 15) == 0) {
        redm[w * 4 + (l >> 4)] = dmsq;
        redr[w * 4 + (l >> 4)] = r2s;
    }
    __syncthreads();

    if (tid < 64) {
        float m = redm[tid];
        float r = redr[tid];
        #pragma unroll
        for (int s = 1; s < 64; s <<= 1) {
            m  = fmaxf(m, __shfl_xor(m, s));
            r += __shfl_xor(r, s);
        }
        if (tid == 0) {
            out[b]      = sqrtf(fmaxf(m, 0.f)) * (1.0f / CC);   // M
            out[BB + b] = r * (1.0f / (CC * CC));               // R2 = sum(maxsq)/1024
        }
    }
}

extern "C" void kernel_launch(void* const* d_in, const int* in_sizes, int n_in,
                              void* d_out, int out_size, void* d_ws, size_t ws_size,
                              hipStream_t stream) {
    const float* x  = (const float*)d_in[0];   // (32,1024,32) fp32
    // d_in[1] is w == 32, hardcoded
    float* out = (float*)d_out;                // 64 floats: M(32) ++ R2(32)

    sm_onepass<<<dim3(BB), 1024, 0, stream>>>(x, out);
}

// Round 6
// 10.810 us; speedup vs baseline: 2.3770x; 1.6150x over previous
//
#include <hip/hip_runtime.h>
#include <math.h>

// SmoothedMedian: B=32, L=1024, C=32, w=32
// out[0..31] = M (per-batch max over t of windowed max distance)
// out[32..63] = R2 (per-batch sum over t of (windowed max distance)^2)
//
// Kernel 1 (512 blocks x 256 thr): per (batch, 64-center tile), banded Gram
// via split-bf16 MFMA (verified rounds 3-5, absmax 0.0):
//   x = hi + lo (bit-truncate);  G ~= Ah*Bh + Ah*Bl + Al*Bh  (err ~2^-16 rel)
//   sq(t,r) = n_t + n_r - 2*G[t,r]  (norms exact fp32)
// Block partial = (max_t maxsq, sum_t maxsq) -> ws slot. No atomics/fences.
// Kernel 2 (1 block x 512 thr): slot t read as one coalesced float2,
// 16-lane shuffle tree per batch (fixed order => deterministic),
// M = sqrt(max)/32, R2 = sum/1024.
// mfma_f32_16x16x32_bf16: A lane l -> row l&15, k=(l>>4)*8+j (K-contig);
// B lane l -> col l&15, same k; D: col=l&15, row=(l>>4)*4+reg  [m89/m91].

#define BB 32
#define LL 1024
#define CC 32
#define WW 32
#define TT 64
#define NROWS (TT + 2*WW)     // 128
#define PADH 40               // bf16 elems/row (80 B): 16B-aligned, bank-spread
#define NTILES (LL / TT)      // 16
#define NBLK (BB * NTILES)    // 512

typedef __attribute__((ext_vector_type(8))) short bf16x8;
typedef __attribute__((ext_vector_type(4))) float f32x4;

__global__ __launch_bounds__(256)
void sm_main(const float* __restrict__ x, float* __restrict__ ws) {
    const int b    = blockIdx.x;
    const int tile = blockIdx.y;
    const int t0   = tile * TT;
    const int tid  = threadIdx.x;   // 0..255
    const int l    = tid & 63;      // lane
    const int w    = tid >> 6;      // wave 0..3

    __shared__ __align__(16) unsigned short hi[NROWS * PADH];
    __shared__ __align__(16) unsigned short lo[NROWS * PADH];
    __shared__ __align__(16) float nrm_part[NROWS * 8];
    __shared__ float nrm[NROWS];
    __shared__ float redm[16], redr[16];

    const float* xb = x + (size_t)b * (LL * CC);

    // --- stage 128 rows x 32 ch: fp32 load, split to bf16 hi/lo, norm partials ---
    #pragma unroll
    for (int k = 0; k < 4; ++k) {
        const int f4 = tid + k * 256;      // 0..1023
        const int rr = f4 >> 3;            // local row (8 float4/row)
        const int j  = f4 & 7;
        const int rg = t0 - WW + rr;       // global row
        float4 v = make_float4(0.f, 0.f, 0.f, 0.f);
        if ((unsigned)rg < (unsigned)LL)
            v = *reinterpret_cast<const float4*>(xb + rg * CC + j * 4);
        float vv[4] = {v.x, v.y, v.z, v.w};
        unsigned short hb[4], lb[4];
        float s = 0.f;
        #pragma unroll
        for (int e = 0; e < 4; ++e) {
            const float xe = vv[e];
            const unsigned ux = __float_as_uint(xe);
            hb[e] = (unsigned short)(ux >> 16);                  // truncate to bf16
            const float hf = __uint_as_float(ux & 0xFFFF0000u);
            const float lf = xe - hf;                            // exact residual
            lb[e] = (unsigned short)(__float_as_uint(lf) >> 16);
            s = fmaf(xe, xe, s);
        }
        *reinterpret_cast<ushort4*>(&hi[rr * PADH + j * 4]) = make_ushort4(hb[0], hb[1], hb[2], hb[3]);
        *reinterpret_cast<ushort4*>(&lo[rr * PADH + j * 4]) = make_ushort4(lb[0], lb[1], lb[2], lb[3]);
        nrm_part[f4] = s;
    }
    __syncthreads();

    if (tid < NROWS) {
        const float4* p = reinterpret_cast<const float4*>(&nrm_part[tid * 8]);
        const float4 a = p[0], c = p[1];
        nrm[tid] = ((a.x + a.y) + (a.z + a.w)) + ((c.x + c.y) + (c.z + c.w));
    }
    __syncthreads();

    // --- A-frag: wave w's 16 centers (local rows 32+16w .. 47+16w) ---
    const int kc = (l >> 4) * 8;
    const int ar = 32 + 16 * w + (l & 15);
    const bf16x8 Ah = *reinterpret_cast<const bf16x8*>(&hi[ar * PADH + kc]);
    const bf16x8 Al = *reinterpret_cast<const bf16x8*>(&lo[ar * PADH + kc]);

    const int col = l & 15;
    float maxsq[4] = {0.f, 0.f, 0.f, 0.f};   // o==0 contributes ~0; floor 0 correct

    // center norms are invariant across the ct loop — hoist
    float ncr[4];
    #pragma unroll
    for (int i = 0; i < 4; ++i)
        ncr[i] = nrm[32 + 16 * w + (l >> 4) * 4 + i];

    // window rows for wave w's centers span local [16w, 16w+79] -> 5 B-tiles
    #pragma unroll
    for (int ct = 0; ct < 5; ++ct) {
        const int br = 16 * w + 16 * ct + col;   // local window row (this lane's col)
        const bf16x8 Bh = *reinterpret_cast<const bf16x8*>(&hi[br * PADH + kc]);
        const bf16x8 Bl = *reinterpret_cast<const bf16x8*>(&lo[br * PADH + kc]);
        f32x4 acc = {0.f, 0.f, 0.f, 0.f};
        acc = __builtin_amdgcn_mfma_f32_16x16x32_bf16(Ah, Bh, acc, 0, 0, 0);
        acc = __builtin_amdgcn_mfma_f32_16x16x32_bf16(Ah, Bl, acc, 0, 0, 0);
        acc = __builtin_amdgcn_mfma_f32_16x16x32_bf16(Al, Bh, acc, 0, 0, 0);

        const int rg = t0 - WW + br;             // global window row
        const float nr = nrm[br];
        #pragma unroll
        for (int i = 0; i < 4; ++i) {
            const int ic = 16 * w + (l >> 4) * 4 + i;   // center index 0..63
            // valid window: br in [ic, ic+64]; global row in [0,L)
            if (br >= ic && br <= ic + 64 && (unsigned)rg < (unsigned)LL) {
                const float sq = ncr[i] + nr - 2.0f * acc[i];
                maxsq[i] = fmaxf(maxsq[i], sq);
            }
        }
    }

    // --- 16-lane (col) reduce; per-(wave,group) partials in maxsq domain ---
    #pragma unroll
    for (int i = 0; i < 4; ++i) {
        float m = maxsq[i];
        #pragma unroll
        for (int s = 1; s < 16; s <<= 1) m = fmaxf(m, __shfl_xor(m, s));
        maxsq[i] = m;
    }
    if ((l & 15) == 0) {
        float dm = maxsq[0], r2 = maxsq[0];
        #pragma unroll
        for (int i = 1; i < 4; ++i) {
            dm = fmaxf(dm, maxsq[i]);
            r2 += maxsq[i];
        }
        redm[w * 4 + (l >> 4)] = dm;
        redr[w * 4 + (l >> 4)] = r2;
    }
    __syncthreads();

    if (tid == 0) {
        float dm = redm[0], r2 = redr[0];
        #pragma unroll
        for (int g = 1; g < 16; ++g) { dm = fmaxf(dm, redm[g]); r2 += redr[g]; }
        reinterpret_cast<float2*>(ws)[b * NTILES + tile] = make_float2(dm, r2);
    }
}

__global__ __launch_bounds__(512)
void sm_reduce(const float* __restrict__ ws, float* __restrict__ out) {
    const int t = threadIdx.x;                 // 0..511, slot index
    const float2 v = reinterpret_cast<const float2*>(ws)[t];   // one coalesced burst
    float m = v.x;    // max of maxsq over this tile
    float r = v.y;    // sum of maxsq over this tile
    #pragma unroll
    for (int s = 1; s < 16; s <<= 1) {         // reduce the 16 tiles of a batch
        m = fmaxf(m, __shfl_xor(m, s));
        r += __shfl_xor(r, s);
    }
    if ((t & 15) == 0) {
        const int b = t >> 4;
        out[b]      = sqrtf(fmaxf(m, 0.f)) * (1.0f / CC);   // M
        out[BB + b] = r * (1.0f / (CC * CC));               // R2 = sum(maxsq)/1024
    }
}

extern "C" void kernel_launch(void* const* d_in, const int* in_sizes, int n_in,
                              void* d_out, int out_size, void* d_ws, size_t ws_size,
                              hipStream_t stream) {
    const float* x  = (const float*)d_in[0];   // (32,1024,32) fp32
    // d_in[1] is w == 32, hardcoded
    float* ws  = (float*)d_ws;                 // 512 float2 slots = 4 KB
    float* out = (float*)d_out;                // 64 floats: M(32) ++ R2(32)

    sm_main<<<dim3(BB, NTILES), 256, 0, stream>>>(x, ws);
    sm_reduce<<<1, 512, 0, stream>>>(ws, out);
}